// Round 1
// baseline (810.462 us; speedup 1.0000x reference)
//
#include <hip/hip_runtime.h>
#include <hip/hip_bf16.h>

// Problem constants
#define T_TOK 1024
#define H_DIM 2048
#define I_DIM 768
#define E_NUM 32
#define K_TOP 4
#define NPAIR (T_TOK * K_TOP)          // 4096 routed (token, expert) pairs
#define TM 32                          // tokens per m-tile
#define MAX_SLOTS (NPAIR + E_NUM * TM) // 5120 (worst-case padding)

// ws layout (byte offsets)
#define WS_META   0                                   // int[512]
#define WS_TOKEN  2048                                // int[MAX_SLOTS]
#define WS_WEIGHT (WS_TOKEN + MAX_SLOTS * 4)          // float[MAX_SLOTS]
#define WS_HBUF   (WS_WEIGHT + MAX_SLOTS * 4)         // bf16[MAX_SLOTS][I_DIM]
#define WS_XB     (WS_HBUF + MAX_SLOTS * I_DIM * 2)   // bf16[T_TOK][H_DIM]

typedef __bf16 bf16x8 __attribute__((ext_vector_type(8)));
typedef float f32x4 __attribute__((ext_vector_type(4)));
typedef float f32x8 __attribute__((ext_vector_type(8)));

__device__ inline bf16x8 cvt8(f32x8 v) {
    bf16x8 r;
#pragma unroll
    for (int i = 0; i < 8; ++i) r[i] = (__bf16)v[i];
    return r;
}

// ---------------------------------------------------------------------------
// Routing: group (token,k) pairs by expert, pad each expert to multiple of TM.
// meta: [0]=total slots; [8+e]=slot base off[e]; [64+e]=ntiles[e]. Single block.
// ---------------------------------------------------------------------------
__global__ void moe_route(const int* __restrict__ ids,
                          const float* __restrict__ ew,
                          int* __restrict__ meta,
                          int* __restrict__ slot_tok,
                          float* __restrict__ slot_w) {
    __shared__ int cnt[E_NUM], off[E_NUM], cur[E_NUM];
    __shared__ int s_tot;
    const int tid = threadIdx.x;
    if (tid < E_NUM) cnt[tid] = 0;
    __syncthreads();
    for (int p = tid; p < NPAIR; p += blockDim.x)
        atomicAdd(&cnt[ids[p]], 1);
    __syncthreads();
    if (tid == 0) {
        int tot = 0;
        for (int e = 0; e < E_NUM; ++e) {
            int pad = (cnt[e] + TM - 1) / TM * TM;
            off[e] = tot;
            meta[8 + e]  = tot;        // slot base of expert e
            meta[64 + e] = pad / TM;   // m-tile count of expert e
            tot += pad;
        }
        meta[0] = tot;
        s_tot = tot;
    }
    __syncthreads();
    const int tot = s_tot;
    for (int s = tid; s < tot; s += blockDim.x) {
        slot_tok[s] = 0;     // padded slots point at token 0 with weight 0
        slot_w[s]   = 0.0f;
    }
    if (tid < E_NUM) cur[tid] = 0;
    __syncthreads();
    for (int p = tid; p < NPAIR; p += blockDim.x) {
        int e = ids[p];
        int i = atomicAdd(&cur[e], 1);
        int s = off[e] + i;
        slot_tok[s] = p / K_TOP;
        slot_w[s]   = ew[p];
    }
}

// ---------------------------------------------------------------------------
// One-time X fp32 -> bf16 cast (X is reused by every routed slot; 8 MB -> 4 MB
// and removes 2 cvt8/m-tile/k-step of VALU from the hot gateup loop).
// ---------------------------------------------------------------------------
__global__ __launch_bounds__(256) void moe_xcast(const float* __restrict__ X,
                                                 __hip_bfloat16* __restrict__ Xb) {
    const int i = (blockIdx.x * 256 + threadIdx.x) * 8;
    f32x8 v = *(const f32x8*)(X + i);
    *(bf16x8*)(void*)(Xb + i) = cvt8(v);
}

// ---------------------------------------------------------------------------
// Phase 1: h = silu(X Wg^T) * (X Wu^T), weight-read-once structure.
// Block = (expert, 32-col chunk of I). Wave w: cols n0+16*(w&1), m-tiles
// (w>>1)::2. K outermost, all group m-tiles accumulate in registers, so each
// weight byte is loaded from HBM exactly once (no cache reliance).
// ---------------------------------------------------------------------------
template<int NMT>
__device__ __forceinline__ void gu_group(
    const __hip_bfloat16* __restrict__ Xb,
    const float* __restrict__ pg, const float* __restrict__ pu,
    const int* __restrict__ slot_tok,
    __hip_bfloat16* __restrict__ Hb,
    int off, int tile0, int n0, int col, int quad) {
    int s0[NMT];
    const __hip_bfloat16 *px0[NMT], *px1[NMT];
#pragma unroll
    for (int m = 0; m < NMT; ++m) {
        s0[m] = off + TM * (tile0 + 2 * m);
        px0[m] = Xb + (size_t)slot_tok[s0[m] + col] * H_DIM;
        px1[m] = Xb + (size_t)slot_tok[s0[m] + 16 + col] * H_DIM;
    }
    f32x4 ag0[NMT], ag1[NMT], au0[NMT], au1[NMT];
#pragma unroll
    for (int m = 0; m < NMT; ++m) {
        ag0[m] = {0.f,0.f,0.f,0.f}; ag1[m] = {0.f,0.f,0.f,0.f};
        au0[m] = {0.f,0.f,0.f,0.f}; au1[m] = {0.f,0.f,0.f,0.f};
    }
    for (int k = quad * 8; k < H_DIM; k += 32) {
        bf16x8 bg = cvt8(*(const f32x8*)(pg + k));
        bf16x8 bu = cvt8(*(const f32x8*)(pu + k));
#pragma unroll
        for (int m = 0; m < NMT; ++m) {
            bf16x8 a0 = *(const bf16x8*)(const void*)(px0[m] + k);
            bf16x8 a1 = *(const bf16x8*)(const void*)(px1[m] + k);
            ag0[m] = __builtin_amdgcn_mfma_f32_16x16x32_bf16(a0, bg, ag0[m], 0, 0, 0);
            ag1[m] = __builtin_amdgcn_mfma_f32_16x16x32_bf16(a1, bg, ag1[m], 0, 0, 0);
            au0[m] = __builtin_amdgcn_mfma_f32_16x16x32_bf16(a0, bu, au0[m], 0, 0, 0);
            au1[m] = __builtin_amdgcn_mfma_f32_16x16x32_bf16(a1, bu, au1[m], 0, 0, 0);
        }
    }
#pragma unroll
    for (int m = 0; m < NMT; ++m) {
#pragma unroll
        for (int r = 0; r < 4; ++r) {
            const int row = quad * 4 + r;
            float g0 = ag0[m][r], u0 = au0[m][r];
            float h0 = (g0 / (1.0f + __expf(-g0))) * u0;
            Hb[(size_t)(s0[m] + row) * I_DIM + n0 + col] = __float2bfloat16(h0);
            float g1 = ag1[m][r], u1 = au1[m][r];
            float h1 = (g1 / (1.0f + __expf(-g1))) * u1;
            Hb[(size_t)(s0[m] + 16 + row) * I_DIM + n0 + col] = __float2bfloat16(h1);
        }
    }
}

__global__ __launch_bounds__(256) void moe_gateup(
    const __hip_bfloat16* __restrict__ Xb,
    const float* __restrict__ Wg,
    const float* __restrict__ Wu,
    const int* __restrict__ meta,
    const int* __restrict__ slot_tok,
    __hip_bfloat16* __restrict__ Hb) {
    const int NCH = I_DIM / 32;  // 24
    const int e   = blockIdx.x / NCH;
    const int nch = blockIdx.x - e * NCH;
    const int lane = threadIdx.x & 63;
    const int wave = threadIdx.x >> 6;
    const int col  = lane & 15;
    const int quad = lane >> 4;
    const int colg = wave & 1;
    const int half = wave >> 1;
    const int n0 = nch * 32 + colg * 16;

    const int off   = meta[8 + e];
    const int ntile = meta[64 + e];
    const int nw = (ntile > half) ? ((ntile - half + 1) >> 1) : 0;
    if (nw == 0) return;  // wave-uniform; no __syncthreads in this kernel

    const size_t wrow = ((size_t)e * I_DIM + n0 + col) * H_DIM;
    const float* pg = Wg + wrow;
    const float* pu = Wu + wrow;

    for (int i0 = 0; i0 < nw; i0 += 3) {
        int g = nw - i0; if (g > 3) g = 3;
        const int tile0 = half + 2 * i0;
        switch (g) {
            case 1:  gu_group<1>(Xb, pg, pu, slot_tok, Hb, off, tile0, n0, col, quad); break;
            case 2:  gu_group<2>(Xb, pg, pu, slot_tok, Hb, off, tile0, n0, col, quad); break;
            default: gu_group<3>(Xb, pg, pu, slot_tok, Hb, off, tile0, n0, col, quad); break;
        }
    }
}

// ---------------------------------------------------------------------------
// Phase 2: y[t] += w * (h @ Wd^T), same weight-read-once structure.
// Block = (expert, 32-col chunk of H); wave w: cols n0+16*(w&1), tiles (w>>1)::2.
// ---------------------------------------------------------------------------
template<int NMT>
__device__ __forceinline__ void dn_group(
    const float* __restrict__ pd,
    const int* __restrict__ slot_tok,
    const float* __restrict__ slot_w,
    const __hip_bfloat16* __restrict__ Hb,
    float* __restrict__ Y,
    int off, int tile0, int n0, int col, int quad) {
    int s0[NMT];
    const __hip_bfloat16 *ph0[NMT], *ph1[NMT];
#pragma unroll
    for (int m = 0; m < NMT; ++m) {
        s0[m] = off + TM * (tile0 + 2 * m);
        ph0[m] = Hb + (size_t)(s0[m] + col) * I_DIM;
        ph1[m] = Hb + (size_t)(s0[m] + 16 + col) * I_DIM;
    }
    f32x4 a0[NMT], a1[NMT];
#pragma unroll
    for (int m = 0; m < NMT; ++m) { a0[m] = {0.f,0.f,0.f,0.f}; a1[m] = {0.f,0.f,0.f,0.f}; }

    for (int k = quad * 8; k < I_DIM; k += 32) {
        bf16x8 b = cvt8(*(const f32x8*)(pd + k));
#pragma unroll
        for (int m = 0; m < NMT; ++m) {
            bf16x8 h0 = *(const bf16x8*)(const void*)(ph0[m] + k);
            bf16x8 h1 = *(const bf16x8*)(const void*)(ph1[m] + k);
            a0[m] = __builtin_amdgcn_mfma_f32_16x16x32_bf16(h0, b, a0[m], 0, 0, 0);
            a1[m] = __builtin_amdgcn_mfma_f32_16x16x32_bf16(h1, b, a1[m], 0, 0, 0);
        }
    }
#pragma unroll
    for (int m = 0; m < NMT; ++m) {
#pragma unroll
        for (int r = 0; r < 4; ++r) {
            const int row = quad * 4 + r;
            const int sA = s0[m] + row;
            atomicAdd(&Y[(size_t)slot_tok[sA] * H_DIM + n0 + col], a0[m][r] * slot_w[sA]);
            const int sB = s0[m] + 16 + row;
            atomicAdd(&Y[(size_t)slot_tok[sB] * H_DIM + n0 + col], a1[m][r] * slot_w[sB]);
        }
    }
}

__global__ __launch_bounds__(256) void moe_down(
    const float* __restrict__ Wd,
    const int* __restrict__ meta,
    const int* __restrict__ slot_tok,
    const float* __restrict__ slot_w,
    const __hip_bfloat16* __restrict__ Hb,
    float* __restrict__ Y) {
    const int NCH = H_DIM / 32;  // 64
    const int e   = blockIdx.x / NCH;
    const int nch = blockIdx.x - e * NCH;
    const int lane = threadIdx.x & 63;
    const int wave = threadIdx.x >> 6;
    const int col  = lane & 15;
    const int quad = lane >> 4;
    const int colg = wave & 1;
    const int half = wave >> 1;
    const int n0 = nch * 32 + colg * 16;

    const int off   = meta[8 + e];
    const int ntile = meta[64 + e];
    const int nw = (ntile > half) ? ((ntile - half + 1) >> 1) : 0;
    if (nw == 0) return;

    const float* pd = Wd + ((size_t)e * H_DIM + n0 + col) * I_DIM;

    for (int i0 = 0; i0 < nw; i0 += 3) {
        int g = nw - i0; if (g > 3) g = 3;
        const int tile0 = half + 2 * i0;
        switch (g) {
            case 1:  dn_group<1>(pd, slot_tok, slot_w, Hb, Y, off, tile0, n0, col, quad); break;
            case 2:  dn_group<2>(pd, slot_tok, slot_w, Hb, Y, off, tile0, n0, col, quad); break;
            default: dn_group<3>(pd, slot_tok, slot_w, Hb, Y, off, tile0, n0, col, quad); break;
        }
    }
}

extern "C" void kernel_launch(void* const* d_in, const int* in_sizes, int n_in,
                              void* d_out, int out_size, void* d_ws, size_t ws_size,
                              hipStream_t stream) {
    const float* X  = (const float*)d_in[0];
    const float* Wg = (const float*)d_in[1];
    const float* Wu = (const float*)d_in[2];
    const float* Wd = (const float*)d_in[3];
    const int* ids  = (const int*)d_in[4];
    const float* ew = (const float*)d_in[5];

    char* ws = (char*)d_ws;
    int*   meta     = (int*)(ws + WS_META);
    int*   slot_tok = (int*)(ws + WS_TOKEN);
    float* slot_w   = (float*)(ws + WS_WEIGHT);
    __hip_bfloat16* Hb = (__hip_bfloat16*)(ws + WS_HBUF);
    __hip_bfloat16* Xb = (__hip_bfloat16*)(ws + WS_XB);
    float* Y = (float*)d_out;  // fp32 output (reference returns float32)

    // d_out is re-poisoned before every timed launch — zero it ourselves.
    hipMemsetAsync(Y, 0, (size_t)T_TOK * H_DIM * sizeof(float), stream);
    moe_route<<<1, 256, 0, stream>>>(ids, ew, meta, slot_tok, slot_w);
    moe_xcast<<<(T_TOK * H_DIM / 8) / 256, 256, 0, stream>>>(X, Xb);
    moe_gateup<<<E_NUM * (I_DIM / 32), 256, 0, stream>>>(Xb, Wg, Wu, meta, slot_tok, Hb);
    moe_down<<<E_NUM * (H_DIM / 32), 256, 0, stream>>>(Wd, meta, slot_tok, slot_w, Hb, Y);
}